// Round 2
// baseline (79.883 us; speedup 1.0000x reference)
//
#include <hip/hip_runtime.h>
#include <math.h>

// 4-qubit, 2-layer circuit, batch-parallel statevector sim — single fused kernel.
// One thread per batch element; 16 complex amps in registers.
// Wire w <-> bit (8>>w) of the flat index (q0 is MSB, matching (B,2,2,2,2) C-order).
// Weight trig (batch-uniform, 8 angles) is recomputed per-thread: ~64 uniform VALU
// ops/thread beats a serialized 1-block producer kernel + launch gap + d_ws traffic.

// CNOT(ctrl->tgt): where ctrl bit set, swap tgt-bit pair. Pure register permutation.
#define CNOT(cb, tb)                                                  \
    {                                                                 \
        _Pragma("unroll") for (int i = 0; i < 16; i++)                \
            if ((i & (cb)) && !(i & (tb))) {                          \
                int j = i | (tb);                                     \
                float t;                                              \
                t = re[i]; re[i] = re[j]; re[j] = t;                  \
                t = im[i]; im[i] = im[j]; im[j] = t;                  \
            }                                                         \
    }

// RY(theta) on wire `bit`: real rotation on re and im independently.
// 2 instr per output value (v_mul + v_fma with sign modifier).
#define RY(bit, cc, ss)                                               \
    {                                                                 \
        _Pragma("unroll") for (int i = 0; i < 16; i++)                \
            if (!(i & (bit))) {                                       \
                int j = i | (bit);                                    \
                float r0 = re[i], r1 = re[j];                         \
                float i0 = im[i], i1 = im[j];                         \
                re[i] = __builtin_fmaf((cc), r0, -((ss) * r1));       \
                re[j] = __builtin_fmaf((ss), r0, (cc) * r1);          \
                im[i] = __builtin_fmaf((cc), i0, -((ss) * i1));       \
                im[j] = __builtin_fmaf((ss), i0, (cc) * i1);          \
            }                                                         \
    }

__global__ __launch_bounds__(256) void qc_kernel(const float* __restrict__ noise,
                                                 const float* __restrict__ weights,
                                                 float* __restrict__ out, int B) {
    int b = blockIdx.x * blockDim.x + threadIdx.x;
    if (b >= B) return;

    // Batch-uniform weight trig: weights loads become s_load; sincos is uniform VALU.
    float wc[8], wsn[8];
#pragma unroll
    for (int i = 0; i < 8; i++) {
        float th = weights[i] * 0.5f;
        __sincosf(th, &wsn[i], &wc[i]);
    }

    // Coalesced 16B load of this element's 4 RX angles.
    float4 nv = reinterpret_cast<const float4*>(noise)[b];
    float c0, s0, c1, s1, c2, s2, c3, s3;
    __sincosf(nv.x * 0.5f, &s0, &c0);
    __sincosf(nv.y * 0.5f, &s1, &c1);
    __sincosf(nv.z * 0.5f, &s2, &c2);
    __sincosf(nv.w * 0.5f, &s3, &c3);

    // Post-RX product state: amp(i) = prod(c/s) * (-i)^popcount(i).
    float m01[4], m23[4];
    m01[0] = c0 * c1; m01[1] = c0 * s1; m01[2] = s0 * c1; m01[3] = s0 * s1;
    m23[0] = c2 * c3; m23[1] = c2 * s3; m23[2] = s2 * c3; m23[3] = s2 * s3;

    float re[16], im[16];
#pragma unroll
    for (int i = 0; i < 16; i++) {
        float m = m01[i >> 2] * m23[i & 3];
        int pc = __popc(i) & 3;
        re[i] = (pc == 0) ? m : (pc == 2) ? -m : 0.0f;
        im[i] = (pc == 1) ? -m : (pc == 3) ? m : 0.0f;
    }

    // 2 layers: CNOT ring (0->1,1->2,2->3,3->0) then RY on each wire.
#pragma unroll
    for (int layer = 0; layer < 2; layer++) {
        CNOT(8, 4);   // ctrl 0, tgt 1
        CNOT(4, 2);   // ctrl 1, tgt 2
        CNOT(2, 1);   // ctrl 2, tgt 3
        CNOT(1, 8);   // ctrl 3, tgt 0
        RY(8, wc[layer * 4 + 0], wsn[layer * 4 + 0]);
        RY(4, wc[layer * 4 + 1], wsn[layer * 4 + 1]);
        RY(2, wc[layer * 4 + 2], wsn[layer * 4 + 2]);
        RY(1, wc[layer * 4 + 3], wsn[layer * 4 + 3]);
    }

    // out[b][w] = sum of |amp|^2 over indices with wire-w bit clear.
    float p[16];
#pragma unroll
    for (int i = 0; i < 16; i++) p[i] = __builtin_fmaf(im[i], im[i], re[i] * re[i]);

    // Shared group sums: g_x = sum over i>>2 == x, h_y = sum over i&3 == y.
    float g[4], h[4];
#pragma unroll
    for (int x = 0; x < 4; x++)
        g[x] = ((p[4 * x + 0] + p[4 * x + 1]) + (p[4 * x + 2] + p[4 * x + 3]));
#pragma unroll
    for (int y = 0; y < 4; y++)
        h[y] = ((p[y] + p[y + 4]) + (p[y + 8] + p[y + 12]));

    float o0 = g[0] + g[1];   // bit8 clear
    float o1 = g[0] + g[2];   // bit4 clear
    float o2 = h[0] + h[1];   // bit2 clear
    float o3 = h[0] + h[2];   // bit1 clear
    reinterpret_cast<float4*>(out)[b] = make_float4(o0, o1, o2, o3);
}

extern "C" void kernel_launch(void* const* d_in, const int* in_sizes, int n_in,
                              void* d_out, int out_size, void* d_ws, size_t ws_size,
                              hipStream_t stream) {
    const float* noise   = (const float*)d_in[0];   // (B, 4)
    const float* weights = (const float*)d_in[1];   // (2, 4)
    float* out = (float*)d_out;                     // (B, 4)
    int B = in_sizes[0] / 4;

    qc_kernel<<<(B + 255) / 256, 256, 0, stream>>>(noise, weights, out, B);
}

// Round 4
// 70.112 us; speedup vs baseline: 1.1394x; 1.1394x over previous
//
#include <hip/hip_runtime.h>
#include <math.h>

// 4-qubit, 2-layer circuit — CLOSED FORM via Heisenberg/Pauli backpropagation.
// NOT cyclically symmetric (CNOT ring order matters); each wire derived
// independently. Images through the reversed CNOT ring T:
//   T(Z0)=Z1Z2Z3 T(Z1)=Z0Z1 T(Z2)=Z0Z1Z2 T(Z3)=Z0Z1Z2Z3
//   T(X0)=X0X1   T(X1)=X1X2 T(X2)=X2X3   T(X3)=X0X1X3   <- note X1!
// Evaluate on RX product state: <X>=0, <Z_v>=z_v=cos n_v, <Y_v>=-y_v=-sin n_v.
// All surviving terms verified term-by-term vs direct single-angle Heisenberg
// probes + weights=0 GF(2) parity + |+>^4 + |1111> global checks.
//
// <Z0> = C10C03[C01C02 z0z1z3 + C01S02 y2y3 - S01S02 z0y1z2y3]
//      + S10   [C00S01 y0y1   + S00C01 y1y2z3 - S00S01 z0z2z3]
// <Z1> = C11[C00C01 z0z2z3 + C00S01 y1y2z3 + S00C01 y0y1]
//      + S11S02[C01 z0y1y2 - S01 z2]
// <Z2> = C12[C00C01C02 z1z3 + C00C01S02 z0y2y3 - C00S01S02 y1z2y3
//            - S00S01C02 y0z1y2]
//      + S12S03[C02 z0z1y2y3 - S02 z3]
// <Z3> = C13C03[C00C01C02 z0z2 + C00S01C02 y1y2 + S00C01C02 y0y1z3
//               + S00S01S02 y0z1z2y3]
//      + S13S03[C00C01 y0z1y2z3 - S00S01 z1]
// out_w = (1 + <Z_w>)/2

__global__ __launch_bounds__(256) void qc_kernel(const float* __restrict__ noise,
                                                 const float* __restrict__ weights,
                                                 float* __restrict__ out, int B) {
    int b = blockIdx.x * blockDim.x + threadIdx.x;
    if (b >= B) return;

    // Batch-uniform weight trig (full angles); loads fold to s_load, trig +
    // coefficient products are ~90 uniform VALU ops/thread.
    float C0[4], S0[4], C1[4], S1[4];
#pragma unroll
    for (int v = 0; v < 4; v++) {
        __sincosf(weights[v],     &S0[v], &C0[v]);
        __sincosf(weights[4 + v], &S1[v], &C1[v]);
    }

    // Uniform coefficients (signs folded in).
    float A0 = C1[0] * C0[3];
    float K01 = A0 * C0[1] * C0[2], K02 = A0 * C0[1] * S0[2], K03 = -A0 * S0[1] * S0[2];
    float K04 = S1[0] * C0[0] * S0[1], K05 = S1[0] * S0[0] * C0[1], K06 = -S1[0] * S0[0] * S0[1];

    float K11 = C1[1] * C0[0] * C0[1], K12 = C1[1] * C0[0] * S0[1], K13 = C1[1] * S0[0] * C0[1];
    float B1 = S1[1] * S0[2];
    float K14 = B1 * C0[1], K15 = -B1 * S0[1];

    float A2 = C1[2] * C0[0];
    float K21 = A2 * C0[1] * C0[2], K22 = A2 * C0[1] * S0[2], K23 = -A2 * S0[1] * S0[2];
    float K24 = -C1[2] * S0[0] * S0[1] * C0[2];
    float B2 = S1[2] * S0[3];
    float K25 = B2 * C0[2], K26 = -B2 * S0[2];

    float A3 = C1[3] * C0[3] * C0[2];
    float K31 = A3 * C0[0] * C0[1], K32 = A3 * C0[0] * S0[1], K33 = A3 * S0[0] * C0[1];
    float K34 = C1[3] * C0[3] * S0[0] * S0[1] * S0[2];
    float B3 = S1[3] * S0[3];
    float K35 = B3 * C0[0] * C0[1], K36 = -B3 * S0[0] * S0[1];

    // Per-element: coalesced 16B load of the 4 RX angles; full-angle trig.
    float4 nv = reinterpret_cast<const float4*>(noise)[b];
    float z0, z1, z2, z3, y0, y1, y2, y3;
    __sincosf(nv.x, &y0, &z0);
    __sincosf(nv.y, &y1, &z1);
    __sincosf(nv.z, &y2, &z2);
    __sincosf(nv.w, &y3, &z3);

    // Shared pair products.
    float z01 = z0 * z1, z02 = z0 * z2, z12 = z1 * z2, z13 = z1 * z3;
    float y01 = y0 * y1, y12 = y1 * y2, y23 = y2 * y3;
    float y02 = y0 * y2, y13 = y1 * y3, y03 = y0 * y3;

    float Z0 = K01 * (z01 * z3);
    Z0 = __builtin_fmaf(K02, y23, Z0);
    Z0 = __builtin_fmaf(K03, z02 * y13, Z0);
    Z0 = __builtin_fmaf(K04, y01, Z0);
    Z0 = __builtin_fmaf(K05, y12 * z3, Z0);
    Z0 = __builtin_fmaf(K06, z02 * z3, Z0);

    float Z1 = K11 * (z02 * z3);
    Z1 = __builtin_fmaf(K12, y12 * z3, Z1);
    Z1 = __builtin_fmaf(K13, y01, Z1);
    Z1 = __builtin_fmaf(K14, z0 * y12, Z1);
    Z1 = __builtin_fmaf(K15, z2, Z1);

    float Z2 = K21 * z13;
    Z2 = __builtin_fmaf(K22, z0 * y23, Z2);
    Z2 = __builtin_fmaf(K23, y13 * z2, Z2);
    Z2 = __builtin_fmaf(K24, y02 * z1, Z2);
    Z2 = __builtin_fmaf(K25, z01 * y23, Z2);
    Z2 = __builtin_fmaf(K26, z3, Z2);

    float Z3 = K31 * z02;
    Z3 = __builtin_fmaf(K32, y12, Z3);
    Z3 = __builtin_fmaf(K33, y01 * z3, Z3);
    Z3 = __builtin_fmaf(K34, y03 * z12, Z3);
    Z3 = __builtin_fmaf(K35, y02 * z13, Z3);
    Z3 = __builtin_fmaf(K36, z1, Z3);

    reinterpret_cast<float4*>(out)[b] =
        make_float4(__builtin_fmaf(0.5f, Z0, 0.5f), __builtin_fmaf(0.5f, Z1, 0.5f),
                    __builtin_fmaf(0.5f, Z2, 0.5f), __builtin_fmaf(0.5f, Z3, 0.5f));
}

extern "C" void kernel_launch(void* const* d_in, const int* in_sizes, int n_in,
                              void* d_out, int out_size, void* d_ws, size_t ws_size,
                              hipStream_t stream) {
    const float* noise   = (const float*)d_in[0];   // (B, 4)
    const float* weights = (const float*)d_in[1];   // (2, 4)
    float* out = (float*)d_out;                     // (B, 4)
    int B = in_sizes[0] / 4;

    qc_kernel<<<(B + 255) / 256, 256, 0, stream>>>(noise, weights, out, B);
}